// Round 6
// baseline (82.923 us; speedup 1.0000x reference)
//
#include <hip/hip_runtime.h>
#include <math.h>

#define N 384
#define DF 128
#define TI 16
#define TK 16
#define TEMP 2.0f
#define SOFT_LAMBDA 0.5f
#define BETA 1.0f
#define EPS_COS 1e-8f
#define EPS_LOG 1e-7f

// ---------------------------------------------------------------------------
// Kernel A: pairwise tables (SoA): td/rd/eo/lo, each [N*N].
// 24x24 blocks of 16x16 pairs, 256 threads (round-3 structure, measured best).
// Also zeroes d_out for kernel B's atomics (kernel boundary orders it).
// ---------------------------------------------------------------------------
__global__ __launch_bounds__(256) void rnc_pairs(
    const float* __restrict__ feat,   // [N, DF]
    const float* __restrict__ rg,     // [N, 3]
    const float* __restrict__ rr,     // [N, 3]
    const float* __restrict__ tr,     // [N, 3]
    const int*   __restrict__ sym,    // [N]
    float* __restrict__ ptd,          // [N*N]
    float* __restrict__ prd,          // [N*N]
    float* __restrict__ peo,          // [N*N]
    float* __restrict__ plo,          // [N*N]
    float* __restrict__ out)
{
    const int i0 = blockIdx.y * TI;
    const int k0 = blockIdx.x * TK;
    const int t = threadIdx.x;

    __shared__ __align__(16) float4 fi_s[TI][DF / 4 + 1];
    __shared__ __align__(16) float4 fk_s[TK][DF / 4 + 1];
    __shared__ float4 hi_s[TI], gi_s[TI], ri_s[TI];
    __shared__ float4 hk_s[TK], gk_s[TK], rk_s[TK];

    if (blockIdx.x == 0 && blockIdx.y == 0 && t == 0) out[0] = 0.f;

    if (t < TI) {
        int g = i0 + t;
        hi_s[t] = make_float4(tr[g * 3], tr[g * 3 + 1], tr[g * 3 + 2],
                              (sym[g] == 1) ? 1.f : 0.f);
        float a = rg[g * 3], b = rg[g * 3 + 1], c = rg[g * 3 + 2];
        gi_s[t] = make_float4(a, b, c, fmaxf(sqrtf(a * a + b * b + c * c), EPS_COS));
        float d = rr[g * 3], e = rr[g * 3 + 1], f = rr[g * 3 + 2];
        ri_s[t] = make_float4(d, e, f, fmaxf(sqrtf(d * d + e * e + f * f), EPS_COS));
    } else if (t >= 32 && t < 32 + TK) {
        int g = k0 + (t - 32);
        int tl = t - 32;
        hk_s[tl] = make_float4(tr[g * 3], tr[g * 3 + 1], tr[g * 3 + 2],
                               (sym[g] == 1) ? 1.f : 0.f);
        float a = rg[g * 3], b = rg[g * 3 + 1], c = rg[g * 3 + 2];
        gk_s[tl] = make_float4(a, b, c, fmaxf(sqrtf(a * a + b * b + c * c), EPS_COS));
        float d = rr[g * 3], e = rr[g * 3 + 1], f = rr[g * 3 + 2];
        rk_s[tl] = make_float4(d, e, f, fmaxf(sqrtf(d * d + e * e + f * f), EPS_COS));
    }

    const float4* feat4 = reinterpret_cast<const float4*>(feat);
#pragma unroll
    for (int idx = 0; idx < 2; ++idx) {
        int u = t + idx * 256;            // 0..511 over 16 rows x 32 f4
        int row = u >> 5, c = u & 31;
        fi_s[row][c] = feat4[(i0 + row) * (DF / 4) + c];
        fk_s[row][c] = feat4[(k0 + row) * (DF / 4) + c];
    }
    __syncthreads();

    const int ii = t >> 4, kk = t & 15;
    float sq = 0.f;
#pragma unroll
    for (int d = 0; d < DF / 4; ++d) {
        float4 a = fi_s[ii][d];
        float4 b = fk_s[kk][d];
        float dx = a.x - b.x, dy = a.y - b.y, dz = a.z - b.z, dw = a.w - b.w;
        sq += dx * dx + dy * dy + dz * dz + dw * dw;
    }
    const int gi = i0 + ii, gk = k0 + kk;
    float dist = (sq > 0.f) ? sqrtf(sq) : 0.f;
    float lo = -dist * (1.0f / TEMP);
    float eo = (gi == gk) ? 0.f : expf(lo);

    float4 ha = hi_s[ii], hb = hk_s[kk];
    float d0 = ha.x - hb.x, d1 = ha.y - hb.y, d2 = ha.z - hb.z;
    float a0 = fabsf(d0), a1 = fabsf(d1), a2 = fabsf(d2);
    float s = ((a0 < BETA) ? (0.5f * d0 * d0 / BETA) : (a0 - 0.5f * BETA))
            + ((a1 < BETA) ? (0.5f * d1 * d1 / BETA) : (a1 - 0.5f * BETA))
            + ((a2 < BETA) ? (0.5f * d2 * d2 / BETA) : (a2 - 0.5f * BETA));
    float td = s * (1.0f / 3.0f);

    float4 ga = gi_s[ii], gb = gk_s[kk];
    float gdiff = 1.0f - (ga.x * gb.x + ga.y * gb.y + ga.z * gb.z) / (ga.w * gb.w);
    float4 ra = ri_s[ii], rb = rk_s[kk];
    float rdiff = 1.0f - (ra.x * rb.x + ra.y * rb.y + ra.z * rb.z) / (ra.w * rb.w);
    bool pair_sym = (ha.w != 0.f) || (hb.w != 0.f);
    float rd = pair_sym ? gdiff : (gdiff + rdiff);

    const int idx = gi * N + gk;
    ptd[idx] = td;
    prd[idx] = rd;
    peo[idx] = eo;
    plo[idx] = lo;
}

// ---------------------------------------------------------------------------
// Kernel B: rank denominators + pos terms + atomic reduction.
// 768 blocks (row i = b>>1, j-half h = b&1; 3 blocks/CU balanced) x 512
// threads (8 waves). Lane l holds 3 j's in registers; wave w covers
// k in [w*48, w*48+48). SoA in LDS: 4 k's per 3 broadcast ds_read_b128
// -> LDS issue ~= VALU floor (~4.3 us each, balanced pipes).
// ---------------------------------------------------------------------------
__global__ __launch_bounds__(512) void rnc_rank(
    const float* __restrict__ ptd,
    const float* __restrict__ prd,
    const float* __restrict__ peo,
    const float* __restrict__ plo,
    float* __restrict__ out)
{
    const int i = blockIdx.x >> 1;
    const int h = blockIdx.x & 1;
    const int t = threadIdx.x;

    __shared__ __align__(16) float td_s[N];
    __shared__ __align__(16) float rd_s[N];
    __shared__ __align__(16) float eo_s[N];
    __shared__ float dpt[8][192];   // [wave][j_local], conflict-free columns
    __shared__ float dph[8][192];
    __shared__ float red_h[8], red_t[8];

    // stage row i (3 x 96 float4 loads)
    if (t < 96) {
        reinterpret_cast<float4*>(td_s)[t] =
            reinterpret_cast<const float4*>(ptd + i * N)[t];
    } else if (t < 192) {
        reinterpret_cast<float4*>(rd_s)[t - 96] =
            reinterpret_cast<const float4*>(prd + i * N)[t - 96];
    } else if (t < 288) {
        reinterpret_cast<float4*>(eo_s)[t - 192] =
            reinterpret_cast<const float4*>(peo + i * N)[t - 192];
    }
    __syncthreads();

    const int w = t >> 6, l = t & 63;
    const int jl = l * 3;                 // local j base 0..189
    float tdj[3], rdj[3];
    float dent[3] = {0.f, 0.f, 0.f};
    float denh[3] = {0.f, 0.f, 0.f};
#pragma unroll
    for (int jj = 0; jj < 3; ++jj) {
        tdj[jj] = td_s[h * 192 + jl + jj];
        rdj[jj] = rd_s[h * 192 + jl + jj];
    }

    const float4* td4 = reinterpret_cast<const float4*>(td_s);
    const float4* rd4 = reinterpret_cast<const float4*>(rd_s);
    const float4* eo4 = reinterpret_cast<const float4*>(eo_s);
    const int k4b = w * 12;               // 48 k's = 12 float4 per wave
#pragma unroll 4
    for (int k4 = k4b; k4 < k4b + 12; ++k4) {
        float4 tv = td4[k4];              // wave-uniform -> broadcast
        float4 rv = rd4[k4];
        float4 ev = eo4[k4];
#pragma unroll
        for (int jj = 0; jj < 3; ++jj) {
            bool m0 = tv.x >= tdj[jj];
            bool m1 = tv.y >= tdj[jj];
            bool m2 = tv.z >= tdj[jj];
            bool m3 = tv.w >= tdj[jj];
            dent[jj] += m0 ? ev.x : 0.f;
            dent[jj] += m1 ? ev.y : 0.f;
            dent[jj] += m2 ? ev.z : 0.f;
            dent[jj] += m3 ? ev.w : 0.f;
            denh[jj] += (m0 && rv.x >= rdj[jj]) ? ev.x : 0.f;
            denh[jj] += (m1 && rv.y >= rdj[jj]) ? ev.y : 0.f;
            denh[jj] += (m2 && rv.z >= rdj[jj]) ? ev.z : 0.f;
            denh[jj] += (m3 && rv.w >= rdj[jj]) ? ev.w : 0.f;
        }
    }
#pragma unroll
    for (int jj = 0; jj < 3; ++jj) {
        dpt[w][jl + jj] = dent[jj];
        dph[w][jl + jj] = denh[jj];
    }
    __syncthreads();

    float pos_h = 0.f, pos_t = 0.f;
    if (t < 192) {
        const int j = h * 192 + t;
        if (j != i) {
            float st_ = 0.f, sh_ = 0.f;
#pragma unroll
            for (int g = 0; g < 8; ++g) {
                st_ += dpt[g][t];   // consecutive t -> consecutive banks
                sh_ += dph[g][t];
            }
            float lo = plo[i * N + j];   // coalesced, L2-hit
            pos_h = lo - logf(sh_ + EPS_LOG);
            pos_t = lo - logf(st_ + EPS_LOG);
        }
    }
#pragma unroll
    for (int off = 32; off > 0; off >>= 1) {
        pos_h += __shfl_down(pos_h, off, 64);
        pos_t += __shfl_down(pos_t, off, 64);
    }
    if (l == 0) {
        red_h[w] = pos_h;
        red_t[w] = pos_t;
    }
    __syncthreads();
    if (t == 0) {
        float sh = 0.f, st = 0.f;
#pragma unroll
        for (int g = 0; g < 8; ++g) {
            sh += red_h[g];
            st += red_t[g];
        }
        const float scale = -1.0f / ((float)N * (float)(N - 1));
        atomicAdd(out, (sh + SOFT_LAMBDA * st) * scale);
    }
}

extern "C" void kernel_launch(void* const* d_in, const int* in_sizes, int n_in,
                              void* d_out, int out_size, void* d_ws, size_t ws_size,
                              hipStream_t stream) {
    const float* feat = (const float*)d_in[0];  // [384,128]
    const float* rg   = (const float*)d_in[1];  // [384,3]
    const float* rr   = (const float*)d_in[2];  // [384,3]
    const float* tr   = (const float*)d_in[3];  // [384,3]
    const int*   sym  = (const int*)d_in[4];    // [384,1]
    float* out = (float*)d_out;

    float* ptd = (float*)d_ws;                  // 4 x N*N floats = 2.36 MB
    float* prd = ptd + (size_t)N * N;
    float* peo = prd + (size_t)N * N;
    float* plo = peo + (size_t)N * N;

    dim3 gridA(N / TK, N / TI);
    rnc_pairs<<<gridA, 256, 0, stream>>>(feat, rg, rr, tr, sym, ptd, prd, peo, plo, out);
    rnc_rank<<<2 * N, 512, 0, stream>>>(ptd, prd, peo, plo, out);
}

// Round 7
// 81.784 us; speedup vs baseline: 1.0139x; 1.0139x over previous
//
#include <hip/hip_runtime.h>
#include <math.h>

#define N 384
#define DF 128
#define TI 16
#define TK 16
#define TEMP 2.0f
#define SOFT_LAMBDA 0.5f
#define BETA 1.0f
#define EPS_COS 1e-8f
#define EPS_LOG 1e-7f

// ---------------------------------------------------------------------------
// Kernel A (round-3 structure, measured best): pairwise table
// pk[i][k] = {td, rd, eo (0 on diag), lo}. 24x24 blocks of 16x16 pairs,
// 256 threads. Also zeroes d_out for kernel B's atomics.
// ---------------------------------------------------------------------------
__global__ __launch_bounds__(256) void rnc_pairs(
    const float* __restrict__ feat,   // [N, DF]
    const float* __restrict__ rg,     // [N, 3]
    const float* __restrict__ rr,     // [N, 3]
    const float* __restrict__ tr,     // [N, 3]
    const int*   __restrict__ sym,    // [N]
    float4* __restrict__ pk,          // [N*N]
    float* __restrict__ out)
{
    const int i0 = blockIdx.y * TI;
    const int k0 = blockIdx.x * TK;
    const int t = threadIdx.x;

    __shared__ __align__(16) float4 fi_s[TI][DF / 4 + 1];
    __shared__ __align__(16) float4 fk_s[TK][DF / 4 + 1];
    __shared__ float4 hi_s[TI], gi_s[TI], ri_s[TI];
    __shared__ float4 hk_s[TK], gk_s[TK], rk_s[TK];

    if (blockIdx.x == 0 && blockIdx.y == 0 && t == 0) out[0] = 0.f;

    if (t < TI) {
        int g = i0 + t;
        hi_s[t] = make_float4(tr[g * 3], tr[g * 3 + 1], tr[g * 3 + 2],
                              (sym[g] == 1) ? 1.f : 0.f);
        float a = rg[g * 3], b = rg[g * 3 + 1], c = rg[g * 3 + 2];
        gi_s[t] = make_float4(a, b, c, fmaxf(sqrtf(a * a + b * b + c * c), EPS_COS));
        float d = rr[g * 3], e = rr[g * 3 + 1], f = rr[g * 3 + 2];
        ri_s[t] = make_float4(d, e, f, fmaxf(sqrtf(d * d + e * e + f * f), EPS_COS));
    } else if (t >= 32 && t < 32 + TK) {
        int g = k0 + (t - 32);
        int tl = t - 32;
        hk_s[tl] = make_float4(tr[g * 3], tr[g * 3 + 1], tr[g * 3 + 2],
                               (sym[g] == 1) ? 1.f : 0.f);
        float a = rg[g * 3], b = rg[g * 3 + 1], c = rg[g * 3 + 2];
        gk_s[tl] = make_float4(a, b, c, fmaxf(sqrtf(a * a + b * b + c * c), EPS_COS));
        float d = rr[g * 3], e = rr[g * 3 + 1], f = rr[g * 3 + 2];
        rk_s[tl] = make_float4(d, e, f, fmaxf(sqrtf(d * d + e * e + f * f), EPS_COS));
    }

    const float4* feat4 = reinterpret_cast<const float4*>(feat);
#pragma unroll
    for (int idx = 0; idx < 2; ++idx) {
        int u = t + idx * 256;            // 0..511 over 16 rows x 32 f4
        int row = u >> 5, c = u & 31;
        fi_s[row][c] = feat4[(i0 + row) * (DF / 4) + c];
        fk_s[row][c] = feat4[(k0 + row) * (DF / 4) + c];
    }
    __syncthreads();

    const int ii = t >> 4, kk = t & 15;
    float sq = 0.f;
#pragma unroll
    for (int d = 0; d < DF / 4; ++d) {
        float4 a = fi_s[ii][d];
        float4 b = fk_s[kk][d];
        float dx = a.x - b.x, dy = a.y - b.y, dz = a.z - b.z, dw = a.w - b.w;
        sq += dx * dx + dy * dy + dz * dz + dw * dw;
    }
    const int gi = i0 + ii, gk = k0 + kk;
    float dist = (sq > 0.f) ? sqrtf(sq) : 0.f;
    float lo = -dist * (1.0f / TEMP);
    float eo = (gi == gk) ? 0.f : expf(lo);

    float4 ha = hi_s[ii], hb = hk_s[kk];
    float d0 = ha.x - hb.x, d1 = ha.y - hb.y, d2 = ha.z - hb.z;
    float a0 = fabsf(d0), a1 = fabsf(d1), a2 = fabsf(d2);
    float s = ((a0 < BETA) ? (0.5f * d0 * d0 / BETA) : (a0 - 0.5f * BETA))
            + ((a1 < BETA) ? (0.5f * d1 * d1 / BETA) : (a1 - 0.5f * BETA))
            + ((a2 < BETA) ? (0.5f * d2 * d2 / BETA) : (a2 - 0.5f * BETA));
    float td = s * (1.0f / 3.0f);

    float4 ga = gi_s[ii], gb = gk_s[kk];
    float gdiff = 1.0f - (ga.x * gb.x + ga.y * gb.y + ga.z * gb.z) / (ga.w * gb.w);
    float4 ra = ri_s[ii], rb = rk_s[kk];
    float rdiff = 1.0f - (ra.x * rb.x + ra.y * rb.y + ra.z * rb.z) / (ra.w * rb.w);
    bool pair_sym = (ha.w != 0.f) || (hb.w != 0.f);
    float rd = pair_sym ? gdiff : (gdiff + rdiff);

    pk[gi * N + gk] = make_float4(td, rd, eo, lo);
}

// ---------------------------------------------------------------------------
// Kernel B (round-3 structure + atomic fold + conflict-free partials):
// 768 blocks (row i = b>>1, j-half h = b&1) x 512 threads. Lane l holds 3 j's;
// wave w covers k in [w*48, w*48+48); one broadcast ds_read_b128 per k.
// Partials in [wave][j_local] float arrays: stage-3 reads at consecutive t
// hit consecutive banks (round-3's [j][wave] float2 was 32-way conflicted).
// ---------------------------------------------------------------------------
__global__ __launch_bounds__(512) void rnc_rank(
    const float4* __restrict__ pk,
    float* __restrict__ out)
{
    const int i = blockIdx.x >> 1;
    const int h = blockIdx.x & 1;
    const int t = threadIdx.x;

    __shared__ __align__(16) float4 pks[N];   // 6 KB
    __shared__ float dpt[8][192];             // 6 KB, conflict-free columns
    __shared__ float dph[8][192];             // 6 KB
    __shared__ float red_h[8], red_t[8];

    if (t < N) pks[t] = pk[i * N + t];
    __syncthreads();

    const int w = t >> 6, l = t & 63;
    const int jl = l * 3;                 // local j base 0..189
    float tdj[3], rdj[3];
    float dent[3] = {0.f, 0.f, 0.f};
    float denh[3] = {0.f, 0.f, 0.f};
#pragma unroll
    for (int jj = 0; jj < 3; ++jj) {
        float4 p = pks[h * 192 + jl + jj];
        tdj[jj] = p.x;
        rdj[jj] = p.y;
    }
    const int k0 = w * 48;
#pragma unroll 4
    for (int k = k0; k < k0 + 48; ++k) {
        float4 p = pks[k];  // wave-uniform -> broadcast, conflict-free
#pragma unroll
        for (int jj = 0; jj < 3; ++jj) {
            bool mt = p.x >= tdj[jj];
            bool mh = mt && (p.y >= rdj[jj]);
            dent[jj] += mt ? p.z : 0.f;
            denh[jj] += mh ? p.z : 0.f;
        }
    }
#pragma unroll
    for (int jj = 0; jj < 3; ++jj) {
        dpt[w][jl + jj] = dent[jj];
        dph[w][jl + jj] = denh[jj];
    }
    __syncthreads();

    float pos_h = 0.f, pos_t = 0.f;
    if (t < 192) {
        const int j = h * 192 + t;
        if (j != i) {
            float st_ = 0.f, sh_ = 0.f;
#pragma unroll
            for (int g = 0; g < 8; ++g) {
                st_ += dpt[g][t];   // consecutive t -> consecutive banks
                sh_ += dph[g][t];
            }
            float lo = pks[j].w;
            pos_h = lo - logf(sh_ + EPS_LOG);
            pos_t = lo - logf(st_ + EPS_LOG);
        }
    }
#pragma unroll
    for (int off = 32; off > 0; off >>= 1) {
        pos_h += __shfl_down(pos_h, off, 64);
        pos_t += __shfl_down(pos_t, off, 64);
    }
    if (l == 0) {
        red_h[w] = pos_h;
        red_t[w] = pos_t;
    }
    __syncthreads();
    if (t == 0) {
        float sh = 0.f, st = 0.f;
#pragma unroll
        for (int g = 0; g < 8; ++g) {
            sh += red_h[g];
            st += red_t[g];
        }
        const float scale = -1.0f / ((float)N * (float)(N - 1));
        atomicAdd(out, (sh + SOFT_LAMBDA * st) * scale);
    }
}

extern "C" void kernel_launch(void* const* d_in, const int* in_sizes, int n_in,
                              void* d_out, int out_size, void* d_ws, size_t ws_size,
                              hipStream_t stream) {
    const float* feat = (const float*)d_in[0];  // [384,128]
    const float* rg   = (const float*)d_in[1];  // [384,3]
    const float* rr   = (const float*)d_in[2];  // [384,3]
    const float* tr   = (const float*)d_in[3];  // [384,3]
    const int*   sym  = (const int*)d_in[4];    // [384,1]
    float* out = (float*)d_out;

    float4* pk = (float4*)d_ws;  // 384*384*16 B = 2.36 MB

    dim3 gridA(N / TK, N / TI);
    rnc_pairs<<<gridA, 256, 0, stream>>>(feat, rg, rr, tr, sym, pk, out);
    rnc_rank<<<2 * N, 512, 0, stream>>>(pk, out);
}